// Round 15
// baseline (261.510 us; speedup 1.0000x reference)
//
#include <hip/hip_runtime.h>

#define IDTF 199.0f
#define DTF  (1.0f/199.0f)
#define RING 12

typedef float f4 __attribute__((ext_vector_type(4)));

__device__ __forceinline__ void lds_barrier() {
    asm volatile("s_waitcnt lgkmcnt(0)\n\ts_barrier" ::: "memory");
}
__device__ __forceinline__ float bp(int idx, float v) {
    return __builtin_bit_cast(float,
        __builtin_amdgcn_ds_bpermute(idx, __builtin_bit_cast(int, v)));
}

// ===================== SPIKE + PCR coefficient precompute (fp64) ============
// (unchanged from round 14)
__global__ void k_pcr(float* __restrict__ C) {
    const double cc = 65025.0 / 199.0;   // eps*dt/dx^2 = 255^2/199
    __shared__ double pa[2][256], pb[2][256], pc[2][256];
    __shared__ double AL[8][256], BE[8][256];
    __shared__ double ca[256], cb[256], ccx[256];
    __shared__ double salp0[64], sbet0[64];
    __shared__ double Ah[64], Bh[64], Ch[64];
    __shared__ double AL6[6][64], BE6[6][64];
    const int x = threadIdx.x;

    // ---- Woodbury PK columns (m=0, full 256 fp64 PCR) ----
    {
        double ai = (x == 0) ? 0.0 : -cc;
        double bi = 1.0 + 2.0 * cc;
        double ci = (x == 255) ? 0.0 : -cc;
        int cur = 0;
        pa[0][x] = ai; pb[0][x] = bi; pc[0][x] = ci;
        __syncthreads();
        for (int l = 0; l < 8; l++) {
            int s = 1 << l, xm = (x - s < 0) ? 0 : x - s, xp = (x + s > 255) ? 255 : x + s;
            double al = pa[cur][x] / pb[cur][xm];
            double be = pc[cur][x] / pb[cur][xp];
            AL[l][x] = al; BE[l][x] = be;
            double an = -al * pa[cur][xm];
            double cn = -be * pc[cur][xp];
            double bn = pb[cur][x] - al * pc[cur][xm] - be * pa[cur][xp];
            pa[1 - cur][x] = an; pb[1 - cur][x] = bn; pc[1 - cur][x] = cn;
            __syncthreads();
            cur ^= 1;
        }
        double invd = 1.0 / pb[cur][x];
        __syncthreads();
        int cw = 0;
        pa[0][x] = (x == 0) ? -cc : 0.0;     // r1 = -c e0
        pc[0][x] = (x == 255) ? -cc : 0.0;   // r2 = -c e255
        __syncthreads();
        for (int l = 0; l < 8; l++) {
            int s = 1 << l, xm = (x - s < 0) ? 0 : x - s, xp = (x + s > 255) ? 255 : x + s;
            double n1 = pa[cw][x] - AL[l][x] * pa[cw][xm] - BE[l][x] * pa[cw][xp];
            double n2 = pc[cw][x] - AL[l][x] * pc[cw][xm] - BE[l][x] * pc[cw][xp];
            pa[1 - cw][x] = n1; pc[1 - cw][x] = n2;
            __syncthreads();
            cw ^= 1;
        }
        double t1 = pa[cw][x] * invd, t2 = pc[cw][x] * invd;
        pa[1 - cw][x] = t1; pc[1 - cw][x] = t2;
        __syncthreads();
        double K00 = 1.0 + pa[1 - cw][254], K01 = pc[1 - cw][254];
        double K10 = pa[1 - cw][1],         K11 = 1.0 + pc[1 - cw][1];
        double idet = 1.0 / (K00 * K11 - K01 * K10);
        C[5120 + x] = (float)(t1 * (K11 * idet) + t2 * (-K10 * idet));
        C[5376 + x] = (float)(t1 * (-K01 * idet) + t2 * (K00 * idet));
        __syncthreads();
    }
    // ---- SPIKE coefficients per variant ----
    for (int m = 0; m < 2; m++) {
        double ai, bi, ci;
        if (m == 0) {
            ai = (x == 0) ? 0.0 : -cc;
            bi = 1.0 + 2.0 * cc;
            ci = (x == 255) ? 0.0 : -cc;
        } else {
            if (x == 0 || x == 255) { ai = 0.0; bi = 1.0; ci = 0.0; }
            else {
                ai = (x == 1) ? 0.0 : -cc;
                bi = 1.0 + 2.0 * cc;
                ci = (x == 254) ? 0.0 : -cc;
            }
        }
        ca[x] = ai; cb[x] = bi; ccx[x] = ci;
        __syncthreads();
        float* Cr = C + m * 2560;
        double as_ = 0, cs_ = 0, bs_ = 0, alp2 = 0, bet2 = 0;
        if (x < 64) {
            int r0 = 4 * x;
            double m00 = cb[r0],     m01 = ccx[r0];
            double m10 = ca[r0 + 1], m11 = cb[r0 + 1], m12 = ccx[r0 + 1];
            double m21 = ca[r0 + 2], m22 = cb[r0 + 2];
            double C00 = m11 * m22 - m12 * m21, C01 = -m10 * m22, C02 = m10 * m21;
            double C10 = -m01 * m22, C11 = m00 * m22, C12 = -m00 * m21;
            double C20 = m01 * m12, C21 = -m00 * m12, C22 = m00 * m11 - m01 * m10;
            double det = m00 * C00 + m01 * C01;
            double id = 1.0 / det;
            double Mi[3][3] = {{C00 * id, C10 * id, C20 * id},
                               {C01 * id, C11 * id, C21 * id},
                               {C02 * id, C12 * id, C22 * id}};
            double aL = ca[r0], cR = ccx[r0 + 2];
            double alp[3], bet[3];
            for (int i = 0; i < 3; i++) { alp[i] = Mi[i][0] * aL; bet[i] = Mi[i][2] * cR; }
            salp0[x] = alp[0]; sbet0[x] = bet[0];
            as_ = ca[r0 + 3]; cs_ = ccx[r0 + 3]; bs_ = cb[r0 + 3];
            alp2 = alp[2]; bet2 = bet[2];
            for (int i = 0; i < 3; i++)
                for (int j = 0; j < 3; j++)
                    Cr[(i * 3 + j) * 64 + x] = (float)Mi[i][j];
            for (int i = 0; i < 3; i++) {
                Cr[(9 + i) * 64 + x] = (float)alp[i];
                Cr[(12 + i) * 64 + x] = (float)bet[i];
            }
            Cr[15 * 64 + x] = (float)as_;
            Cr[16 * 64 + x] = (float)cs_;
        }
        __syncthreads();
        if (x < 64) {
            int xp = (x + 1) & 63;
            double a0n = salp0[xp], b0n = sbet0[xp];   // garbage at x=63: cs_=0
            Ah[x] = -as_ * alp2;
            Bh[x] = bs_ - as_ * bet2 - cs_ * a0n;
            Ch[x] = -cs_ * b0n;
        }
        __syncthreads();
        // 6-level fp64 PCR on the 64-unknown reduced tridiagonal
        double bfin = 1.0;
        for (int l = 0; l < 6; l++) {
            int s = 1 << l;
            double an = 0, bn = 1, cn = 0;
            if (x < 64) {
                double Acur = Ah[x], Bcur = Bh[x], Ccur = Ch[x];
                double Am = (x - s >= 0) ? Ah[x - s] : 0.0;
                double Bm = (x - s >= 0) ? Bh[x - s] : 1.0;
                double Cm = (x - s >= 0) ? Ch[x - s] : 0.0;
                double Ap = (x + s < 64) ? Ah[x + s] : 0.0;
                double Bp = (x + s < 64) ? Bh[x + s] : 1.0;
                double Cp = (x + s < 64) ? Ch[x + s] : 0.0;
                double al = (x - s >= 0) ? Acur / Bm : 0.0;
                double be = (x + s < 64) ? Ccur / Bp : 0.0;
                AL6[l][x] = al; BE6[l][x] = be;
                an = -al * Am;
                cn = -be * Cp;
                bn = Bcur - al * Cm - be * Ap;
            }
            __syncthreads();
            if (x < 64) { Ah[x] = an; Bh[x] = bn; Ch[x] = cn; bfin = bn; }
            __syncthreads();
        }
        if (x < 64) {
            for (int p = 0; p < 3; p++) {
                int s2 = 2 * (1 << (2 * p));
                double a0 = AL6[2 * p][x],     b0 = BE6[2 * p][x];
                double a1 = AL6[2 * p + 1][x], b1 = BE6[2 * p + 1][x];
                double am = (x - s2 >= 0) ? AL6[2 * p][x - s2] : 0.0;
                double bm = (x - s2 >= 0) ? BE6[2 * p][x - s2] : 0.0;
                double ap = (x + s2 < 64) ? AL6[2 * p][x + s2] : 0.0;
                double bq = (x + s2 < 64) ? BE6[2 * p][x + s2] : 0.0;
                Cr[(17 + p * 6 + 0) * 64 + x] = (float)(-a1 * am);
                Cr[(17 + p * 6 + 1) * 64 + x] = (float)(a1);
                Cr[(17 + p * 6 + 2) * 64 + x] = (float)(a0 - a1 * bm);
                Cr[(17 + p * 6 + 3) * 64 + x] = (float)(b0 - b1 * ap);
                Cr[(17 + p * 6 + 4) * 64 + x] = (float)(b1);
                Cr[(17 + p * 6 + 5) * 64 + x] = (float)(-b1 * bq);
            }
            Cr[35 * 64 + x] = (float)(1.0 / bfin);
        }
        __syncthreads();
    }
}

// ===================== split scan kernel (SPIKE, fused halo, prefetch) ======
// Structure identical to rounds 13/14 (verified): grid(256)=128 batches x 2
// roles (XCD-paired), 512 thr = 8 waves, 12-slot ring, barrier per 4 steps,
// dedicated writer wave. New: (a) consumer forcings for a whole superstep
// prefetched in one batch (slots are lag-4, barrier-separated; written this
// superstep only at disjoint planes); (b) u0-halo folded into stage 0 via
// gamma = nst0*ncs_shift precomputed per lane -> 4 bpermute rounds per step.
__global__ __launch_bounds__(512, 1) void k_split(const float* __restrict__ W,
        const float* __restrict__ U0, const float* __restrict__ C,
        float* __restrict__ out) {
    const int bid = blockIdx.x;
    const int role = (bid >> 3) & 1;
    const int b = (bid & 7) | ((bid >> 4) << 3);
    const int tid = threadIdx.x;
    const int wv = tid >> 6;
    const int L = tid & 63;

    static const signed char TY[8]      = {0,1,2,3,3,3,3,4};
    static const signed char FMT[2][8]  = {{0,0,0,4,1,3,2,0},{0,0,0,0,1,3,2,0}};
    static const signed char PAT[2][8]  = {{0,0,0,1,1,0,2,0},{0,0,0,0,0,1,1,0}};
    static const signed char PBT[2][8]  = {{0,0,0,0,0,0,1,0},{0,0,0,0,0,0,0,0}};
    static const signed char PUB[2][8]  = {{0,1,2,3,4,5,6,0},{0,1,4,3,5,6,7,0}};
    static const signed char NW[8]      = {0,1,1,0,1,0,0,0};
    static const signed char WGRP[2][2]    = {{2,-1},{0,1}};
    static const signed char WPL[2][2][4]  = {{{3,4,5,6},{0,0,0,0}},
                                              {{2,0,1,3},{4,5,6,7}}};

    const int  ty    = TY[wv];
    const bool isWr  = (ty == 4);
    const bool isIC  = (ty == 0);
    const bool isProd = (ty <= 2);
    const int  fmode = FMT[role][wv];
    const int  pAi = PAT[role][wv], pBi = PBT[role][wv];
    const int  pubP  = PUB[role][wv];
    const bool needW = NW[wv];
    const bool pubDW = (role == 1 && wv == 1);
    const int  mat   = isIC ? 1 : 0;

    // ---- SPIKE coefficients into registers ----
    const float* Cr = C + mat * 2560;
    float fMi[9], nalp[3], nbet[3];
#pragma unroll
    for (int k = 0; k < 9; k++) fMi[k] = Cr[k * 64 + L];
#pragma unroll
    for (int i = 0; i < 3; i++) {
        nalp[i] = -Cr[(9 + i) * 64 + L];
        nbet[i] = -Cr[(12 + i) * 64 + L];
    }
    const float nas = -Cr[15 * 64 + L];
    float nst0v[6], nstA[6], nstB[6];
#pragma unroll
    for (int k = 0; k < 6; k++) {
        nst0v[k] = -Cr[(17 + k) * 64 + L];
        nstA[k]  = -Cr[(23 + k) * 64 + L];
        nstB[k]  = -Cr[(29 + k) * 64 + L];
    }
    const float invdX = Cr[35 * 64 + L];
    // lane-shifted ncs (= -c_s at lane L+m, m=-3..+3); boundary zeros exact
    float ncsm[7];
#pragma unroll
    for (int m = 0; m < 7; m++) ncsm[m] = -Cr[16 * 64 + ((L + m - 3) & 63)];
    // fused stage-0 u0-coefficients: gam[mm] for u0_{L+mm}
    float gam[7];
    gam[0] = nst0v[0] * ncsm[0];   // mm=-2  (m=-3)
    gam[1] = nst0v[1] * ncsm[1];   // mm=-1  (m=-2)
    gam[2] = nst0v[2] * ncsm[2];   // mm= 0  (m=-1, own lane)
    gam[3] = ncsm[3];              // mm=+1  (m=0, own X)
    gam[4] = nst0v[3] * ncsm[4];   // mm=+2  (m=+1)
    gam[5] = nst0v[4] * ncsm[5];   // mm=+3  (m=+2)
    gam[6] = nst0v[5] * ncsm[6];   // mm=+4  (m=+3)
    float npk0[4], npk1[4];
    {
        f4 p0 = *(const f4*)&C[5120 + 4 * L];
        f4 p1 = *(const f4*)&C[5376 + 4 * L];
#pragma unroll
        for (int q = 0; q < 4; q++) { npk0[q] = -p0[q]; npk1[q] = -p1[q]; }
    }
    // bpermute lane indices
    int ixv[6], ixu[6], ixs1[6], ixs2[6];
    {
        const int OV[6] = {-3,-2,-1,1,2,3};
        const int OU[6] = {-2,-1,1,2,3,4};
#pragma unroll
        for (int k = 0; k < 6; k++) {
            ixv[k] = ((L + OV[k]) & 63) << 2;
            ixu[k] = ((L + OU[k]) & 63) << 2;
            ixs1[k] = ((L + OV[k] * 4) & 63) << 2;    // {-12,-8,-4,+4,+8,+12}
            ixs2[k] = ((L + OV[k] * 16) & 63) << 2;   // {-48,-32,-16,+16,+32,+48}
        }
    }
    const int ixm1 = ((L + 63) & 63) << 2;

    __shared__ f4 ring[RING][8][64];   // 96 KB

    // ---- state init ----
    float y[4] = {0.f, 0.f, 0.f, 0.f};
    if (isIC) {
        f4 u0v = *(const f4*)&U0[b * 256 + 4 * L];
#pragma unroll
        for (int q = 0; q < 4; q++) y[q] = u0v[q];
    }
    if (isWr) {
        f4* of4 = (f4*)out;
        size_t rb = (size_t)b * 200 * 768;
#pragma unroll
        for (int g = 0; g < 2; g++) {
            const int wg = WGRP[role][g];
            if (wg < 0) continue;
#pragma unroll
            for (int q = 0; q < 4; q++) {
                int xx = 4 * L + q;
                f4 v = {0.f, 0.f, 0.f, 0.f};
                if (wg == 0) v[1] = U0[b * 256 + xx];
                of4[rb + (size_t)xx * 3 + wg] = v;
            }
        }
    }
    float wprev[4] = {0,0,0,0}, wcur[4] = {0,0,0,0}, wnxt[4] = {0,0,0,0};
    if (needW) {
        f4 w0 = *(const f4*)&W[((size_t)b * 200 + 0) * 256 + 4 * L];
        f4 w1 = *(const f4*)&W[((size_t)b * 200 + 1) * 256 + 4 * L];
#pragma unroll
        for (int q = 0; q < 4; q++) { wprev[q] = w0[q]; wcur[q] = w1[q]; }
    }
    __syncthreads();

    int slot = 1;    // own-t ring slot, wraps at RING
    int wslot = 1;   // writer's tw slot

    for (int s = 0; s <= 51; s++) {
        if (!isWr) {
            // ---- consumer: batch-prefetch this superstep's forcings ----
            f4 paf[4], pbf[4];
            if (!isProd) {
                int sl = slot;
#pragma unroll
                for (int kk = 0; kk < 4; kk++) {
                    const int jj = 4 * s + kk + 1;
                    if (jj >= 5 && jj <= 203) {
                        paf[kk] = ring[sl][pAi][L];
                        pbf[kk] = (fmode == 2) ? ring[sl][pBi][L] : paf[kk];
                        sl = (sl == RING - 1) ? 0 : (sl + 1);
                    }
                }
            }
#pragma unroll
            for (int k = 1; k <= 4; k++) {
                const int j = 4 * s + k;
                const int t = isProd ? j : (j - 4);
                const bool active = isProd ? (j <= 199) : (j >= 5 && j <= 203);
                if (!active) continue;
                float dwv[4] = {0,0,0,0};
                if (needW) {
#pragma unroll
                    for (int q = 0; q < 4; q++) dwv[q] = (wcur[q] - wprev[q]) * IDTF;
                    if (t <= 198) {
                        f4 wn = *(const f4*)&W[((size_t)b * 200 + t + 1) * 256 + 4 * L];
#pragma unroll
                        for (int q = 0; q < 4; q++) wnxt[q] = wn[q];
                    }
                }
                // ---- forcing ----
                float d[4];
                if (isProd) {
                    if (ty == 0) {
#pragma unroll
                        for (int q = 0; q < 4; q++) d[q] = y[q];
                    } else if (ty == 1) {
#pragma unroll
                        for (int q = 0; q < 4; q++) d[q] = fmaf(dwv[q], DTF, y[q]);
                    } else {
#pragma unroll
                        for (int q = 0; q < 4; q++) d[q] = fmaf(dwv[q] * dwv[q], DTF, y[q]);
                    }
                } else {
                    f4 pa = paf[k - 1];
                    f4 pb2 = pbf[k - 1];
#pragma unroll
                    for (int q = 0; q < 4; q++) {
                        float fq;
                        if (fmode == 0)      fq = pa[q];
                        else if (fmode == 1) fq = dwv[q] * pa[q];
                        else if (fmode == 2) fq = pb2[q] * pa[q];
                        else if (fmode == 3) fq = pa[q] * pa[q];
                        else                 fq = pa[q] * pa[q] * pa[q];
                        d[q] = fmaf(fq, DTF, y[q]);
                    }
                }
                // ---- SPIKE solve: B d' = d (4 bpermute rounds) ----
                float u0 = fmaf(fMi[2], d[2], fmaf(fMi[1], d[1], fMi[0] * d[0]));
                float u1 = fmaf(fMi[5], d[2], fmaf(fMi[4], d[1], fMi[3] * d[0]));
                float u2 = fmaf(fMi[8], d[2], fmaf(fMi[7], d[1], fMi[6] * d[0]));
                float v = fmaf(nas, u2, d[3]);
                // round A: fused {halo + stage0}
                float va0 = bp(ixv[0], v), va1 = bp(ixv[1], v), va2 = bp(ixv[2], v);
                float va3 = bp(ixv[3], v), va4 = bp(ixv[4], v), va5 = bp(ixv[5], v);
                float ua0 = bp(ixu[0], u0), ua1 = bp(ixu[1], u0), ua2 = bp(ixu[2], u0);
                float ua3 = bp(ixu[3], u0), ua4 = bp(ixu[4], u0), ua5 = bp(ixu[5], u0);
                float X = fmaf(gam[2], u0, v);
                X = fmaf(nst0v[0], va0, fmaf(nst0v[1], va1, X));
                X = fmaf(nst0v[2], va2, fmaf(nst0v[3], va3, X));
                X = fmaf(nst0v[4], va4, fmaf(nst0v[5], va5, X));
                X = fmaf(gam[0], ua0, fmaf(gam[1], ua1, X));
                X = fmaf(gam[3], ua2, fmaf(gam[4], ua3, X));
                X = fmaf(gam[5], ua4, fmaf(gam[6], ua5, X));
                // round B: stage1 (s=4)
                {
                    float m3 = bp(ixs1[0], X), m2 = bp(ixs1[1], X), m1 = bp(ixs1[2], X);
                    float q1 = bp(ixs1[3], X), q2 = bp(ixs1[4], X), q3 = bp(ixs1[5], X);
                    float t0 = fmaf(nstA[0], m3, fmaf(nstA[1], m2, X));
                    float t1 = fmaf(nstA[2], m1, fmaf(nstA[3], q1, t0));
                    X = fmaf(nstA[4], q2, fmaf(nstA[5], q3, t1));
                }
                // round C: stage2 (s=16)
                {
                    float m3 = bp(ixs2[0], X), m2 = bp(ixs2[1], X), m1 = bp(ixs2[2], X);
                    float q1 = bp(ixs2[3], X), q2 = bp(ixs2[4], X), q3 = bp(ixs2[5], X);
                    float t0 = fmaf(nstB[0], m3, fmaf(nstB[1], m2, X));
                    float t1 = fmaf(nstB[2], m1, fmaf(nstB[3], q1, t0));
                    X = fmaf(nstB[4], q2, fmaf(nstB[5], q3, t1));
                }
                X *= invdX;
                // round D: back-substitution halo
                float Xm = bp(ixm1, X);
                d[0] = fmaf(nalp[0], Xm, fmaf(nbet[0], X, u0));
                d[1] = fmaf(nalp[1], Xm, fmaf(nbet[1], X, u1));
                d[2] = fmaf(nalp[2], Xm, fmaf(nbet[2], X, u2));
                d[3] = X;
                if (!isIC) {   // periodic Woodbury rank-2 correction
                    float s1 = __builtin_bit_cast(float,
                        __builtin_amdgcn_readlane(__builtin_bit_cast(int, d[2]), 63));  // x=254
                    float s2 = __builtin_bit_cast(float,
                        __builtin_amdgcn_readlane(__builtin_bit_cast(int, d[1]), 0));   // x=1
#pragma unroll
                    for (int q = 0; q < 4; q++)
                        d[q] = fmaf(npk0[q], s1, fmaf(npk1[q], s2, d[q]));
                }
#pragma unroll
                for (int q = 0; q < 4; q++) y[q] = d[q];
                // ---- publish ----
                {
                    f4 pk; pk[0] = y[0]; pk[1] = y[1]; pk[2] = y[2]; pk[3] = y[3];
                    ring[slot][pubP][L] = pk;
                }
                if (pubDW) {
                    f4 pk; pk[0] = dwv[0]; pk[1] = dwv[1]; pk[2] = dwv[2]; pk[3] = dwv[3];
                    ring[slot][2][L] = pk;
                }
                if (needW && t <= 198) {
#pragma unroll
                    for (int q = 0; q < 4; q++) { wprev[q] = wcur[q]; wcur[q] = wnxt[q]; }
                }
                slot = (slot == RING - 1) ? 0 : (slot + 1);
            }
        } else {
            // ---- writer burst (lag 5-8) ----
            f4* of4 = (f4*)out;
#pragma unroll
            for (int k = 0; k < 4; k++) {
                const int tw = 4 * s - 7 + k;
                if (tw < 1 || tw > 199) continue;
                size_t rb = ((size_t)b * 200 + tw) * 768;
#pragma unroll
                for (int g = 0; g < 2; g++) {
                    const int wg = WGRP[role][g];
                    if (wg < 0) continue;
                    f4 p0 = ring[wslot][WPL[role][g][0]][L];
                    f4 p1 = ring[wslot][WPL[role][g][1]][L];
                    f4 p2 = ring[wslot][WPL[role][g][2]][L];
                    f4 p3 = ring[wslot][WPL[role][g][3]][L];
#pragma unroll
                    for (int q = 0; q < 4; q++) {
                        f4 v; v[0] = p0[q]; v[1] = p1[q]; v[2] = p2[q]; v[3] = p3[q];
                        of4[rb + (size_t)(4 * L + q) * 3 + wg] = v;
                    }
                }
                wslot = (wslot == RING - 1) ? 0 : (wslot + 1);
            }
        }
        lds_barrier();
    }
}

// ===================== launch =====================
extern "C" void kernel_launch(void* const* d_in, const int* in_sizes, int n_in,
                              void* d_out, int out_size, void* d_ws, size_t ws_size,
                              hipStream_t stream) {
    const float* W = (const float*)d_in[0];
    const float* U0 = (const float*)d_in[1];
    float* out = (float*)d_out;
    float* C = (float*)d_ws;   // ~5632 floats = 22.5 KB

    k_pcr<<<1, 256, 0, stream>>>(C);
    k_split<<<dim3(256), 512, 0, stream>>>(W, U0, C, out);
}

// Round 16
// 205.456 us; speedup vs baseline: 1.2728x; 1.2728x over previous
//
#include <hip/hip_runtime.h>

#define IDTF 199.0f
#define DTF  (1.0f/199.0f)
#define RING 12

typedef float f4 __attribute__((ext_vector_type(4)));

__device__ __forceinline__ void lds_barrier() {
    asm volatile("s_waitcnt lgkmcnt(0)\n\ts_barrier" ::: "memory");
}
__device__ __forceinline__ float bp(int idx, float v) {
    return __builtin_bit_cast(float,
        __builtin_amdgcn_ds_bpermute(idx, __builtin_bit_cast(int, v)));
}

// ===================== SPIKE + PCR coefficient precompute (fp64) ============
// B = I - c*A; m=0 truncated-periodic T (corners via Woodbury), m=1 Dirichlet.
// Lane L owns rows 4L..4L+3: interior 4L..4L+2, separator X_L = row 4L+3.
// C layout (floats), per m at m*2560 (rows of 64):
//   rows 0-8: Minv[i][j]; 9-11: alpha_i; 12-14: beta_i; 15: a_s; 16: c_s;
//   rows 17-22: AL6[l] (unfused PCR levels s=1..32); 23-28: BE6[l];
//   row 29: invdX.  Woodbury PK columns (256-wide): C[5120+x], C[5376+x].
__global__ void k_pcr(float* __restrict__ C) {
    const double cc = 65025.0 / 199.0;   // eps*dt/dx^2 = 255^2/199
    __shared__ double pa[2][256], pb[2][256], pc[2][256];
    __shared__ double AL[8][256], BE[8][256];
    __shared__ double ca[256], cb[256], ccx[256];
    __shared__ double salp0[64], sbet0[64];
    __shared__ double Ah[64], Bh[64], Ch[64];
    __shared__ double AL6[6][64], BE6[6][64];
    const int x = threadIdx.x;

    // ---- Woodbury PK columns (m=0, full 256 fp64 PCR) ----
    {
        double ai = (x == 0) ? 0.0 : -cc;
        double bi = 1.0 + 2.0 * cc;
        double ci = (x == 255) ? 0.0 : -cc;
        int cur = 0;
        pa[0][x] = ai; pb[0][x] = bi; pc[0][x] = ci;
        __syncthreads();
        for (int l = 0; l < 8; l++) {
            int s = 1 << l, xm = (x - s < 0) ? 0 : x - s, xp = (x + s > 255) ? 255 : x + s;
            double al = pa[cur][x] / pb[cur][xm];
            double be = pc[cur][x] / pb[cur][xp];
            AL[l][x] = al; BE[l][x] = be;
            double an = -al * pa[cur][xm];
            double cn = -be * pc[cur][xp];
            double bn = pb[cur][x] - al * pc[cur][xm] - be * pa[cur][xp];
            pa[1 - cur][x] = an; pb[1 - cur][x] = bn; pc[1 - cur][x] = cn;
            __syncthreads();
            cur ^= 1;
        }
        double invd = 1.0 / pb[cur][x];
        __syncthreads();
        int cw = 0;
        pa[0][x] = (x == 0) ? -cc : 0.0;     // r1 = -c e0
        pc[0][x] = (x == 255) ? -cc : 0.0;   // r2 = -c e255
        __syncthreads();
        for (int l = 0; l < 8; l++) {
            int s = 1 << l, xm = (x - s < 0) ? 0 : x - s, xp = (x + s > 255) ? 255 : x + s;
            double n1 = pa[cw][x] - AL[l][x] * pa[cw][xm] - BE[l][x] * pa[cw][xp];
            double n2 = pc[cw][x] - AL[l][x] * pc[cw][xm] - BE[l][x] * pc[cw][xp];
            pa[1 - cw][x] = n1; pc[1 - cw][x] = n2;
            __syncthreads();
            cw ^= 1;
        }
        double t1 = pa[cw][x] * invd, t2 = pc[cw][x] * invd;
        pa[1 - cw][x] = t1; pc[1 - cw][x] = t2;
        __syncthreads();
        double K00 = 1.0 + pa[1 - cw][254], K01 = pc[1 - cw][254];
        double K10 = pa[1 - cw][1],         K11 = 1.0 + pc[1 - cw][1];
        double idet = 1.0 / (K00 * K11 - K01 * K10);
        C[5120 + x] = (float)(t1 * (K11 * idet) + t2 * (-K10 * idet));
        C[5376 + x] = (float)(t1 * (-K01 * idet) + t2 * (K00 * idet));
        __syncthreads();
    }
    // ---- SPIKE coefficients per variant ----
    for (int m = 0; m < 2; m++) {
        double ai, bi, ci;
        if (m == 0) {
            ai = (x == 0) ? 0.0 : -cc;
            bi = 1.0 + 2.0 * cc;
            ci = (x == 255) ? 0.0 : -cc;
        } else {
            if (x == 0 || x == 255) { ai = 0.0; bi = 1.0; ci = 0.0; }
            else {
                ai = (x == 1) ? 0.0 : -cc;
                bi = 1.0 + 2.0 * cc;
                ci = (x == 254) ? 0.0 : -cc;
            }
        }
        ca[x] = ai; cb[x] = bi; ccx[x] = ci;
        __syncthreads();
        float* Cr = C + m * 2560;
        double as_ = 0, cs_ = 0, bs_ = 0, alp2 = 0, bet2 = 0;
        if (x < 64) {
            int r0 = 4 * x;
            double m00 = cb[r0],     m01 = ccx[r0];
            double m10 = ca[r0 + 1], m11 = cb[r0 + 1], m12 = ccx[r0 + 1];
            double m21 = ca[r0 + 2], m22 = cb[r0 + 2];
            double C00 = m11 * m22 - m12 * m21, C01 = -m10 * m22, C02 = m10 * m21;
            double C10 = -m01 * m22, C11 = m00 * m22, C12 = -m00 * m21;
            double C20 = m01 * m12, C21 = -m00 * m12, C22 = m00 * m11 - m01 * m10;
            double det = m00 * C00 + m01 * C01;
            double id = 1.0 / det;
            double Mi[3][3] = {{C00 * id, C10 * id, C20 * id},
                               {C01 * id, C11 * id, C21 * id},
                               {C02 * id, C12 * id, C22 * id}};
            double aL = ca[r0], cR = ccx[r0 + 2];
            double alp[3], bet[3];
            for (int i = 0; i < 3; i++) { alp[i] = Mi[i][0] * aL; bet[i] = Mi[i][2] * cR; }
            salp0[x] = alp[0]; sbet0[x] = bet[0];
            as_ = ca[r0 + 3]; cs_ = ccx[r0 + 3]; bs_ = cb[r0 + 3];
            alp2 = alp[2]; bet2 = bet[2];
            for (int i = 0; i < 3; i++)
                for (int j = 0; j < 3; j++)
                    Cr[(i * 3 + j) * 64 + x] = (float)Mi[i][j];
            for (int i = 0; i < 3; i++) {
                Cr[(9 + i) * 64 + x] = (float)alp[i];
                Cr[(12 + i) * 64 + x] = (float)bet[i];
            }
            Cr[15 * 64 + x] = (float)as_;
            Cr[16 * 64 + x] = (float)cs_;
        }
        __syncthreads();
        if (x < 64) {
            int xp = (x + 1) & 63;
            double a0n = salp0[xp], b0n = sbet0[xp];   // garbage at x=63: cs_=0
            Ah[x] = -as_ * alp2;
            Bh[x] = bs_ - as_ * bet2 - cs_ * a0n;
            Ch[x] = -cs_ * b0n;
        }
        __syncthreads();
        // 6-level fp64 PCR on the 64-unknown reduced tridiagonal
        for (int l = 0; l < 6; l++) {
            int s = 1 << l;
            double an = 0, bn = 1, cn = 0;
            if (x < 64) {
                double Acur = Ah[x], Bcur = Bh[x], Ccur = Ch[x];
                double Am = (x - s >= 0) ? Ah[x - s] : 0.0;
                double Bm = (x - s >= 0) ? Bh[x - s] : 1.0;
                double Cm = (x - s >= 0) ? Ch[x - s] : 0.0;
                double Ap = (x + s < 64) ? Ah[x + s] : 0.0;
                double Bp = (x + s < 64) ? Bh[x + s] : 1.0;
                double Cp = (x + s < 64) ? Ch[x + s] : 0.0;
                double al = (x - s >= 0) ? Acur / Bm : 0.0;
                double be = (x + s < 64) ? Ccur / Bp : 0.0;
                AL6[l][x] = al; BE6[l][x] = be;
                an = -al * Am;
                cn = -be * Cp;
                bn = Bcur - al * Cm - be * Ap;
            }
            __syncthreads();
            if (x < 64) { Ah[x] = an; Bh[x] = bn; Ch[x] = cn; }
            __syncthreads();
        }
        if (x < 64) {
            for (int l = 0; l < 6; l++) {
                Cr[(17 + l) * 64 + x] = (float)AL6[l][x];
                Cr[(23 + l) * 64 + x] = (float)BE6[l][x];
            }
            Cr[29 * 64 + x] = (float)(1.0 / Bh[x]);
        }
        __syncthreads();
    }
}

// ===================== split scan kernel (SPIKE, unfused PCR-64) ============
// Structure identical to round 14 (verified, 205us): grid(256)=128 batches x
// 2 roles (XCD-paired), 512 thr = 8 waves, 12-slot ring, barrier per 4 steps,
// dedicated writer wave. Solve: interior 3x3 + UNFUSED 6-level PCR on the
// 64 separators — 13 ds_bpermute/step (level s=32 folds to 1 bp since
// (L+32)&63 == (L-32)&63 and boundary zeros select the valid side).
__global__ __launch_bounds__(512, 1) void k_split(const float* __restrict__ W,
        const float* __restrict__ U0, const float* __restrict__ C,
        float* __restrict__ out) {
    const int bid = blockIdx.x;
    const int role = (bid >> 3) & 1;
    const int b = (bid & 7) | ((bid >> 4) << 3);
    const int tid = threadIdx.x;
    const int wv = tid >> 6;
    const int L = tid & 63;

    static const signed char TY[8]      = {0,1,2,3,3,3,3,4};
    static const signed char FMT[2][8]  = {{0,0,0,4,1,3,2,0},{0,0,0,0,1,3,2,0}};
    static const signed char PAT[2][8]  = {{0,0,0,1,1,0,2,0},{0,0,0,0,0,1,1,0}};
    static const signed char PBT[2][8]  = {{0,0,0,0,0,0,1,0},{0,0,0,0,0,0,0,0}};
    static const signed char PUB[2][8]  = {{0,1,2,3,4,5,6,0},{0,1,4,3,5,6,7,0}};
    static const signed char NW[8]      = {0,1,1,0,1,0,0,0};
    static const signed char WGRP[2][2]    = {{2,-1},{0,1}};
    static const signed char WPL[2][2][4]  = {{{3,4,5,6},{0,0,0,0}},
                                              {{2,0,1,3},{4,5,6,7}}};

    const int  ty    = TY[wv];
    const bool isWr  = (ty == 4);
    const bool isIC  = (ty == 0);
    const bool isProd = (ty <= 2);
    const int  fmode = FMT[role][wv];
    const int  pAi = PAT[role][wv], pBi = PBT[role][wv];
    const int  pubP  = PUB[role][wv];
    const bool needW = NW[wv];
    const bool pubDW = (role == 1 && wv == 1);
    const int  mat   = isIC ? 1 : 0;

    // ---- SPIKE coefficients into registers ----
    const float* Cr = C + mat * 2560;
    float fMi[9], nalp[3], nbet[3];
#pragma unroll
    for (int k = 0; k < 9; k++) fMi[k] = Cr[k * 64 + L];
#pragma unroll
    for (int i = 0; i < 3; i++) {
        nalp[i] = -Cr[(9 + i) * 64 + L];
        nbet[i] = -Cr[(12 + i) * 64 + L];
    }
    const float nas = -Cr[15 * 64 + L];
    const float ncs = -Cr[16 * 64 + L];
    float nal6[6], nbe6[6];
#pragma unroll
    for (int l = 0; l < 6; l++) {
        nal6[l] = -Cr[(17 + l) * 64 + L];
        nbe6[l] = -Cr[(23 + l) * 64 + L];
    }
    const float nc32 = nal6[5] + nbe6[5];   // s=32: both sides read same lane
    const float invdX = Cr[29 * 64 + L];
    float npk0[4], npk1[4];
    {
        f4 p0 = *(const f4*)&C[5120 + 4 * L];
        f4 p1 = *(const f4*)&C[5376 + 4 * L];
#pragma unroll
        for (int q = 0; q < 4; q++) { npk0[q] = -p0[q]; npk1[q] = -p1[q]; }
    }
    // bpermute lane indices (levels s=1,2,4,8,16 two-sided; s=32 single)
    int ixm[5], ixp[5];
#pragma unroll
    for (int l = 0; l < 5; l++) {
        const int s = 1 << l;
        ixm[l] = ((L - s) & 63) << 2;
        ixp[l] = ((L + s) & 63) << 2;
    }
    const int ix32 = ((L + 32) & 63) << 2;

    __shared__ f4 ring[RING][8][64];   // 96 KB

    // ---- state init ----
    float y[4] = {0.f, 0.f, 0.f, 0.f};
    if (isIC) {
        f4 u0v = *(const f4*)&U0[b * 256 + 4 * L];
#pragma unroll
        for (int q = 0; q < 4; q++) y[q] = u0v[q];
    }
    if (isWr) {
        f4* of4 = (f4*)out;
        size_t rb = (size_t)b * 200 * 768;
#pragma unroll
        for (int g = 0; g < 2; g++) {
            const int wg = WGRP[role][g];
            if (wg < 0) continue;
#pragma unroll
            for (int q = 0; q < 4; q++) {
                int xx = 4 * L + q;
                f4 v = {0.f, 0.f, 0.f, 0.f};
                if (wg == 0) v[1] = U0[b * 256 + xx];
                of4[rb + (size_t)xx * 3 + wg] = v;
            }
        }
    }
    float wprev[4] = {0,0,0,0}, wcur[4] = {0,0,0,0}, wnxt[4] = {0,0,0,0};
    if (needW) {
        f4 w0 = *(const f4*)&W[((size_t)b * 200 + 0) * 256 + 4 * L];
        f4 w1 = *(const f4*)&W[((size_t)b * 200 + 1) * 256 + 4 * L];
#pragma unroll
        for (int q = 0; q < 4; q++) { wprev[q] = w0[q]; wcur[q] = w1[q]; }
    }
    __syncthreads();

    int slot = 1;    // own-t ring slot, wraps at RING
    int wslot = 1;   // writer's tw slot

    for (int s = 0; s <= 51; s++) {
        if (!isWr) {
            for (int k = 1; k <= 4; k++) {
                const int j = 4 * s + k;
                const int t = isProd ? j : (j - 4);
                const bool active = isProd ? (j <= 199) : (j >= 5 && j <= 203);
                if (!active) continue;
                float dwv[4] = {0,0,0,0};
                if (needW) {
#pragma unroll
                    for (int q = 0; q < 4; q++) dwv[q] = (wcur[q] - wprev[q]) * IDTF;
                    if (t <= 198) {
                        f4 wn = *(const f4*)&W[((size_t)b * 200 + t + 1) * 256 + 4 * L];
#pragma unroll
                        for (int q = 0; q < 4; q++) wnxt[q] = wn[q];
                    }
                }
                // ---- forcing ----
                float d[4];
                if (isProd) {
                    if (ty == 0) {
#pragma unroll
                        for (int q = 0; q < 4; q++) d[q] = y[q];
                    } else if (ty == 1) {
#pragma unroll
                        for (int q = 0; q < 4; q++) d[q] = fmaf(dwv[q], DTF, y[q]);
                    } else {
#pragma unroll
                        for (int q = 0; q < 4; q++) d[q] = fmaf(dwv[q] * dwv[q], DTF, y[q]);
                    }
                } else {
                    f4 pa = ring[slot][pAi][L];
                    f4 pb2 = (fmode == 2) ? ring[slot][pBi][L] : pa;
#pragma unroll
                    for (int q = 0; q < 4; q++) {
                        float fq;
                        if (fmode == 0)      fq = pa[q];
                        else if (fmode == 1) fq = dwv[q] * pa[q];
                        else if (fmode == 2) fq = pb2[q] * pa[q];
                        else if (fmode == 3) fq = pa[q] * pa[q];
                        else                 fq = pa[q] * pa[q] * pa[q];
                        d[q] = fmaf(fq, DTF, y[q]);
                    }
                }
                // ---- SPIKE solve: B d' = d (13 bpermutes) ----
                float u0 = fmaf(fMi[2], d[2], fmaf(fMi[1], d[1], fMi[0] * d[0]));
                float u1 = fmaf(fMi[5], d[2], fmaf(fMi[4], d[1], fMi[3] * d[0]));
                float u2 = fmaf(fMi[8], d[2], fmaf(fMi[7], d[1], fMi[6] * d[0]));
                float X = fmaf(nas, u2, fmaf(ncs, bp(ixp[0], u0), d[3]));
#pragma unroll
                for (int l = 0; l < 5; l++) {
                    float xm = bp(ixm[l], X), xp = bp(ixp[l], X);
                    X = fmaf(nal6[l], xm, fmaf(nbe6[l], xp, X));
                }
                X = fmaf(nc32, bp(ix32, X), X);
                X *= invdX;
                float Xm = bp(ixm[0], X);
                d[0] = fmaf(nalp[0], Xm, fmaf(nbet[0], X, u0));
                d[1] = fmaf(nalp[1], Xm, fmaf(nbet[1], X, u1));
                d[2] = fmaf(nalp[2], Xm, fmaf(nbet[2], X, u2));
                d[3] = X;
                if (!isIC) {   // periodic Woodbury rank-2 correction
                    float s1 = __builtin_bit_cast(float,
                        __builtin_amdgcn_readlane(__builtin_bit_cast(int, d[2]), 63));  // x=254
                    float s2 = __builtin_bit_cast(float,
                        __builtin_amdgcn_readlane(__builtin_bit_cast(int, d[1]), 0));   // x=1
#pragma unroll
                    for (int q = 0; q < 4; q++)
                        d[q] = fmaf(npk0[q], s1, fmaf(npk1[q], s2, d[q]));
                }
#pragma unroll
                for (int q = 0; q < 4; q++) y[q] = d[q];
                // ---- publish ----
                {
                    f4 pk; pk[0] = y[0]; pk[1] = y[1]; pk[2] = y[2]; pk[3] = y[3];
                    ring[slot][pubP][L] = pk;
                }
                if (pubDW) {
                    f4 pk; pk[0] = dwv[0]; pk[1] = dwv[1]; pk[2] = dwv[2]; pk[3] = dwv[3];
                    ring[slot][2][L] = pk;
                }
                if (needW && t <= 198) {
#pragma unroll
                    for (int q = 0; q < 4; q++) { wprev[q] = wcur[q]; wcur[q] = wnxt[q]; }
                }
                slot = (slot == RING - 1) ? 0 : (slot + 1);
            }
        } else {
            // ---- writer burst (lag 5-8) ----
            f4* of4 = (f4*)out;
#pragma unroll
            for (int k = 0; k < 4; k++) {
                const int tw = 4 * s - 7 + k;
                if (tw < 1 || tw > 199) continue;
                size_t rb = ((size_t)b * 200 + tw) * 768;
#pragma unroll
                for (int g = 0; g < 2; g++) {
                    const int wg = WGRP[role][g];
                    if (wg < 0) continue;
                    f4 p0 = ring[wslot][WPL[role][g][0]][L];
                    f4 p1 = ring[wslot][WPL[role][g][1]][L];
                    f4 p2 = ring[wslot][WPL[role][g][2]][L];
                    f4 p3 = ring[wslot][WPL[role][g][3]][L];
#pragma unroll
                    for (int q = 0; q < 4; q++) {
                        f4 v; v[0] = p0[q]; v[1] = p1[q]; v[2] = p2[q]; v[3] = p3[q];
                        of4[rb + (size_t)(4 * L + q) * 3 + wg] = v;
                    }
                }
                wslot = (wslot == RING - 1) ? 0 : (wslot + 1);
            }
        }
        lds_barrier();
    }
}

// ===================== launch =====================
extern "C" void kernel_launch(void* const* d_in, const int* in_sizes, int n_in,
                              void* d_out, int out_size, void* d_ws, size_t ws_size,
                              hipStream_t stream) {
    const float* W = (const float*)d_in[0];
    const float* U0 = (const float*)d_in[1];
    float* out = (float*)d_out;
    float* C = (float*)d_ws;   // ~5632 floats = 22.5 KB

    k_pcr<<<1, 256, 0, stream>>>(C);
    k_split<<<dim3(256), 512, 0, stream>>>(W, U0, C, out);
}